// Round 13
// baseline (100.728 us; speedup 1.0000x reference)
//
#include <hip/hip_runtime.h>

#define NBINS 101
#define NB2 (2 * NBINS)    // 202 bins total (pos + neg)
#define NTHREADS 256
#define NCOPY 32           // histogram replicas, one per lane&31 (bank = copy)
#define CNT_SHIFT 22
#define QMAX 413695u       // (100<<12) | 4095 : clamps idx to <= 100
#define GSHIFT 38          // global u64 packing: (count << 38) | frac_q12
#define NREP 32            // global accumulator replicas
#define FSCALE 452.5483399593904f   // sqrt(50 * 4096): folds (s+1)*204800 into MFMA

typedef _Float16 half8 __attribute__((ext_vector_type(8)));
typedef float floatx4 __attribute__((ext_vector_type(4)));

// ---------------------------------------------------------------------------
// R22: relaxed-ticket fusion (f16 workspace restored).
// R21 post-mortem: f32-direct doubled hist 21->40.7 (R8 twice-replicated;
// f16 workspace is load-bearing). Calibration: gap ~6us/node-boundary.
// Change vs R15 anchor: delete the finalize NODE via a fully-RELAXED ticket.
// Both prior ticket failures are explained by instructions relaxed does not
// emit: R10 = per-thread threadfence (inv storm); R18 = RELEASE RMW ->
// buffer_wbl2 x528 on a fill-dirtied L2 (FETCH 6.1MB signature). R18 PASSED
// correctness with relaxed gH loads -> release was redundant: __syncthreads
// after the gH atomicAdds drains vmcnt(0), so every device-scope RMW has
// completed at the coherence point before tid0 issues the ticket RMW.
// Ticket order => all RMWs complete before the last block's agent-scope
// relaxed atomic loads (same coherence point). No wbl2/inv/fence anywhere.
// Hist body + binning math byte-identical to R15 -> absmax 0.0.
// ---------------------------------------------------------------------------

__global__ __launch_bounds__(NTHREADS)
void convert_kernel(const float* __restrict__ feats,
                    _Float16* __restrict__ wsF,
                    unsigned long long* __restrict__ gH,  // [NREP][NB2] + ticket
                    int ngroups) {   // N*D/8 groups of 8 floats
    int t = blockIdx.x * NTHREADS + threadIdx.x;
    if (t < ngroups) {
        const float4* p = (const float4*)feats + (size_t)t * 2;
        float4 f0 = p[0];
        float4 f1 = p[1];
        half8 h;
        h[0] = (_Float16)(f0.x * FSCALE); h[1] = (_Float16)(f0.y * FSCALE);
        h[2] = (_Float16)(f0.z * FSCALE); h[3] = (_Float16)(f0.w * FSCALE);
        h[4] = (_Float16)(f1.x * FSCALE); h[5] = (_Float16)(f1.y * FSCALE);
        h[6] = (_Float16)(f1.z * FSCALE); h[7] = (_Float16)(f1.w * FSCALE);
        *(half8*)(wsF + (size_t)t * 8) = h;
    }
    // zero global accumulators + ticket (workspace poisoned each iter);
    // kernel boundary guarantees visibility before hist launches.
    if (t < NREP * NB2 + 1) gH[t] = 0ull;
}

// ---------------------------------------------------------------------------
// One 128x128 upper-triangular tile per BLOCK (R15 body, 4 waves); gH
// epilogue atomics; vmcnt-drained RELAXED ticket; last block finalizes via
// agent-scope relaxed atomic loads. No fences of any kind.
// ---------------------------------------------------------------------------
__global__ __launch_bounds__(NTHREADS, 4)
void hist_finalize_kernel(const _Float16* __restrict__ feats16,
                          const int* __restrict__ classes,
                          unsigned long long* __restrict__ gH,  // [NREP][NB2]
                          unsigned long long* __restrict__ ticket,
                          float* __restrict__ out,
                          int ntiles, int nblocks) {
    __shared__ unsigned lhist[NB2][NCOPY];    // packed count|frac, 25.9 KB
    __shared__ __align__(16) int cls[2][128]; // [A/B][row]
    __shared__ double Cd[NB2];                // finalize scratch (last block)
    __shared__ double Fd[NB2];
    __shared__ double hd[NB2];
    __shared__ int lastflag;

    const int tid = threadIdx.x;
    const int wave = tid >> 6;
    const int lane = tid & 63;

    // zero local histograms (uint4 stores: 1616 x 16B / 256 thr)
    {
        uint4* z = (uint4*)&lhist[0][0];
        uint4 zero = {0u, 0u, 0u, 0u};
        for (int t = tid; t < NB2 * NCOPY / 4; t += NTHREADS) z[t] = zero;
    }

    // decode block -> upper-triangular tile (ti, tj), ntiles = 32
    int ti = 0, tj = 0;
    {
        int rem = blockIdx.x;
        while (rem >= ntiles - ti) { rem -= ntiles - ti; ++ti; }
        tj = ti + rem;
    }
    if (tid < 128)  cls[0][tid]       = classes[ti * 128 + tid];
    else            cls[1][tid - 128] = classes[tj * 128 + (tid - 128)];
    __syncthreads();

    {
        const int i0 = ti * 128, j0 = tj * 128;
        const int lr = lane & 15;
        const int quad = lane >> 4;

        // wave-private A strip (32 rows), block-shared B tile (128 cols)
        const _Float16* Ab = feats16 + (size_t)(i0 + wave * 32 + lr) * 128 + quad * 8;
        const _Float16* Bb = feats16 + (size_t)(j0 + lr) * 128 + quad * 8;

        // acc initialized to the binning bias: (s+1)*204800 + 0.5 rounding
        floatx4 acc[2][8];
        #pragma unroll
        for (int mi = 0; mi < 2; ++mi)
            #pragma unroll
            for (int ni = 0; ni < 8; ++ni) {
                acc[mi][ni][0] = 204800.5f; acc[mi][ni][1] = 204800.5f;
                acc[mi][ni][2] = 204800.5f; acc[mi][ni][3] = 204800.5f;
            }

        #pragma unroll
        for (int ks = 0; ks < 128; ks += 32) {
            half8 af[2];
            #pragma unroll
            for (int mi = 0; mi < 2; ++mi)
                af[mi] = *(const half8*)(Ab + (size_t)mi * 16 * 128 + ks);
            half8 bf[8];
            #pragma unroll
            for (int ni = 0; ni < 8; ++ni)
                bf[ni] = *(const half8*)(Bb + (size_t)ni * 16 * 128 + ks);
            #pragma unroll
            for (int mi = 0; mi < 2; ++mi)
                #pragma unroll
                for (int ni = 0; ni < 8; ++ni)
                    acc[mi][ni] = __builtin_amdgcn_mfma_f32_16x16x32_f16(
                        af[mi], bf[ni], acc[mi][ni], 0, 0, 0);
        }

        // classes for this lane's C fragment rows/cols
        int cA[2][4], cB[8];
        #pragma unroll
        for (int mi = 0; mi < 2; ++mi) {
            int4 c4 = *(const int4*)&cls[0][wave * 32 + mi * 16 + quad * 4];
            cA[mi][0] = c4.x; cA[mi][1] = c4.y;
            cA[mi][2] = c4.z; cA[mi][3] = c4.w;
        }
        #pragma unroll
        for (int ni = 0; ni < 8; ++ni) cB[ni] = cls[1][ni * 16 + lr];

        // binning: acc already equals q + tiny fp noise. One ds_add_u32/pair.
        const int copy = lane & (NCOPY - 1);
        unsigned* hb = &lhist[0][0] + copy;
        const bool diag = (ti == tj);
        #pragma unroll
        for (int mi = 0; mi < 2; ++mi) {
            #pragma unroll
            for (int ni = 0; ni < 8; ++ni) {
                #pragma unroll
                for (int r = 0; r < 4; ++r) {
                    const int li = wave * 32 + mi * 16 + quad * 4 + r;
                    const int lj = ni * 16 + lr;
                    if (diag && li >= lj) continue;  // strict upper triangle
                    float qf = fmaxf(acc[mi][ni][r], 0.0f);
                    unsigned q = (unsigned)qf;
                    q = q > QMAX ? QMAX : q;
                    unsigned idx = q >> 12;
                    unsigned word = (q & 4095u) | (1u << CNT_SHIFT);
                    unsigned hoff = (cA[mi][r] == cB[ni]) ? 0u : (unsigned)NBINS;
                    atomicAdd(hb + (hoff + idx) * NCOPY, word);
                }
            }
        }
    }
    __syncthreads();

    // per-bin unpack: C = sum(w>>22), Fq = sum(w&mask) (q12 fixed point).
    // Max adds per (bin,copy) = 2 lanes * 64 pairs = 128 -> fields safe
    // (cnt <= 128 < 2^10, frac <= 128*4095 < 2^22).
    // Pack (C<<38)|Fq into one u64 atomicAdd; per-block Cs <= 16384 < 2^26,
    // Fq <= 6.7e7 < 2^38; global C 8.39e6 < 2^26, F 3.44e10 < 2^38.
    if (tid < NB2) {
        unsigned Cs = 0, Fq = 0;
        #pragma unroll
        for (int c = 0; c < NCOPY; ++c) {
            unsigned w = lhist[tid][(c + tid) & (NCOPY - 1)];
            Cs += w >> CNT_SHIFT;
            Fq += w & ((1u << CNT_SHIFT) - 1);
        }
        unsigned long long word =
            ((unsigned long long)Cs << GSHIFT) | (unsigned long long)Fq;
        atomicAdd(&gH[(blockIdx.x & (NREP - 1)) * NB2 + tid], word);
    }

    // __syncthreads drains vmcnt(0): this block's device-scope gH RMWs have
    // COMPLETED at the coherence point before tid0 issues the ticket RMW.
    // Fully relaxed -> no buffer_wbl2 (R18's poison), no inv (R10's poison).
    __syncthreads();
    if (tid == 0) {
        unsigned long long old = __hip_atomic_fetch_add(
            ticket, 1ull, __ATOMIC_RELAXED, __HIP_MEMORY_SCOPE_AGENT);
        lastflag = (old == (unsigned long long)(nblocks - 1));
    }
    __syncthreads();
    if (!lastflag) return;

    // ---- finalize on the LAST block (agent-scope relaxed atomic loads;
    //      this exact read path passed correctness in R10 and R18) ----
    {
        const int t = tid;
        if (t < NB2) {
            unsigned long long w = 0ull;
            #pragma unroll
            for (int r = 0; r < NREP; ++r)
                w += __hip_atomic_load(&gH[r * NB2 + t], __ATOMIC_RELAXED,
                                       __HIP_MEMORY_SCOPE_AGENT);
            Cd[t] = (double)(w >> GSHIFT);
            Fd[t] = (double)(w & ((1ull << GSHIFT) - 1)) * (1.0 / 4096.0);
        }
        __syncthreads();
        if (t < NB2) {
            const int lo = (t < NBINS) ? 0 : NBINS;
            const int hi = lo + NBINS - 1;
            double h = Cd[t];
            if (t < hi) h -= Fd[t];
            if (t > lo) h += Fd[t - 1];
            hd[t] = h;
        }
        __syncthreads();
        if (t == 0) {
            double sp = 0.0, sn = 0.0;
            for (int k = 0; k < NBINS; ++k) { sp += hd[k]; sn += hd[NBINS + k]; }
            double isp = 1.0 / sp, isn = 1.0 / sn;
            double cdf = 0.0, res = 0.0;
            for (int k = 0; k < NBINS; ++k) {
                cdf += hd[k] * isp;                   // inclusive cumsum of pos
                res += hd[NBINS + k] * isn * cdf;     // dot with neg
            }
            out[0] = (float)res;
        }
    }
}

extern "C" void kernel_launch(void* const* d_in, const int* in_sizes, int n_in,
                              void* d_out, int out_size, void* d_ws, size_t ws_size,
                              hipStream_t stream) {
    const float* feats   = (const float*)d_in[0];
    const int*   classes = (const int*)d_in[1];
    float* out = (float*)d_out;

    int N = in_sizes[1];                       // 4096
    int D = in_sizes[0] / N;                   // 128
    int ntiles = N / 128;                      // 32
    int nblocks = ntiles * (ntiles + 1) / 2;   // 528 blocks, one tile each
    int ngroups = N * D / 8;                   // 65536 groups of 8 floats

    // workspace layout: f16 scaled feats | u64 gH[NREP][NB2] | u64 ticket
    _Float16* wsF = (_Float16*)d_ws;
    unsigned long long* gH = (unsigned long long*)(wsF + (size_t)N * D);
    unsigned long long* ticket = gH + NREP * NB2;

    int cblocks = (ngroups + NTHREADS - 1) / NTHREADS;
    convert_kernel<<<cblocks, NTHREADS, 0, stream>>>(feats, wsF, gH, ngroups);
    hist_finalize_kernel<<<nblocks, NTHREADS, 0, stream>>>(
        wsF, classes, gH, ticket, out, ntiles, nblocks);
}

// Round 15
// 83.155 us; speedup vs baseline: 1.2113x; 1.2113x over previous
//
#include <hip/hip_runtime.h>

#define NBINS 101
#define NB2 (2 * NBINS)    // 202 bins total (pos + neg)
#define NTHREADS 256
#define NCOPY 32           // histogram replicas, one per lane&31 (bank = copy)
#define CNT_SHIFT 22
#define QMAX 413695u       // (100<<12) | 4095 : clamps idx to <= 100
#define GSHIFT 38          // global u64 packing: (count << 38) | frac_q12
#define NREP 32            // global accumulator replicas
#define FSCALE 452.5483399593904f   // sqrt(50 * 4096): folds (s+1)*204800 into MFMA

typedef _Float16 half8 __attribute__((ext_vector_type(8)));
typedef float floatx4 __attribute__((ext_vector_type(4)));

// ---------------------------------------------------------------------------
// R24: resubmit of R23 (byte-exact R15 anchor: 83.5us, passed, absmax 0.0).
// R23's bench never ran (broker: "MI355X container failed twice" — infra,
// zero information about the code). Retrying the same experiment; changing
// a variable now would confound the re-run.
// Ledger (all measured): in-kernel cross-block finalize poisoned in all
// flavors (R10 threadfence / R18 release / R22 relaxed: +25..40us, L2
// wb/inv storms); coop launch silently no-ops under graph capture (R16/17);
// f32-direct hist +13..19us twice (R8/R21: f16 workspace is load-bearing);
// hist internals insensitive (NREP null R14, traffic/2 +1.1 R15, occup x2
// -9 R20). Final structure: convert -> hist -> finalize (3 nodes, minimum
// legal). Budget at 83.5: 40.4 poison fill (83% HBM peak, harness) +
// ~15-21 hist (L2-latency-bound) + ~4.5 convert+finalize + ~17-20 node
// overhead.
// ---------------------------------------------------------------------------

__global__ __launch_bounds__(NTHREADS)
void convert_kernel(const float* __restrict__ feats,
                    _Float16* __restrict__ wsF,
                    unsigned long long* __restrict__ gH,  // [NREP][NB2]
                    int ngroups) {   // N*D/8 groups of 8 floats
    int t = blockIdx.x * NTHREADS + threadIdx.x;
    if (t < ngroups) {
        const float4* p = (const float4*)feats + (size_t)t * 2;
        float4 f0 = p[0];
        float4 f1 = p[1];
        half8 h;
        h[0] = (_Float16)(f0.x * FSCALE); h[1] = (_Float16)(f0.y * FSCALE);
        h[2] = (_Float16)(f0.z * FSCALE); h[3] = (_Float16)(f0.w * FSCALE);
        h[4] = (_Float16)(f1.x * FSCALE); h[5] = (_Float16)(f1.y * FSCALE);
        h[6] = (_Float16)(f1.z * FSCALE); h[7] = (_Float16)(f1.w * FSCALE);
        *(half8*)(wsF + (size_t)t * 8) = h;
    }
    // zero global accumulators (workspace is poisoned each iteration);
    // the kernel boundary guarantees visibility before hist launches.
    if (t < NREP * NB2) gH[t] = 0ull;
}

// ---------------------------------------------------------------------------
// One 128x128 upper-triangular tile per BLOCK; wave w computes the 32x128
// strip rows [w*32, w*32+32). half8 fragment loads from the scaled f16
// workspace; acc arrives in q-space (bias pre-added); one ds_add_u32 per
// pair; per-block unpack -> one u64 global atomicAdd per bin.
// ---------------------------------------------------------------------------
__global__ __launch_bounds__(NTHREADS, 4)
void hist_pairs_kernel(const _Float16* __restrict__ feats16,
                       const int* __restrict__ classes,
                       unsigned long long* __restrict__ gH,  // [NREP][NB2]
                       int ntiles) {
    __shared__ unsigned lhist[NB2][NCOPY];    // packed count|frac, 25.9 KB
    __shared__ __align__(16) int cls[2][128]; // [A/B][row]

    const int tid = threadIdx.x;
    const int wave = tid >> 6;
    const int lane = tid & 63;

    // zero local histograms (uint4 stores: 1616 x 16B / 256 thr)
    {
        uint4* z = (uint4*)&lhist[0][0];
        uint4 zero = {0u, 0u, 0u, 0u};
        for (int t = tid; t < NB2 * NCOPY / 4; t += NTHREADS) z[t] = zero;
    }

    // decode block -> upper-triangular tile (ti, tj), ntiles = 32
    int ti = 0, tj = 0;
    {
        int rem = blockIdx.x;
        while (rem >= ntiles - ti) { rem -= ntiles - ti; ++ti; }
        tj = ti + rem;
    }
    if (tid < 128)  cls[0][tid]       = classes[ti * 128 + tid];
    else            cls[1][tid - 128] = classes[tj * 128 + (tid - 128)];
    __syncthreads();

    {
        const int i0 = ti * 128, j0 = tj * 128;
        const int lr = lane & 15;
        const int quad = lane >> 4;

        // wave-private A strip (32 rows), block-shared B tile (128 cols)
        const _Float16* Ab = feats16 + (size_t)(i0 + wave * 32 + lr) * 128 + quad * 8;
        const _Float16* Bb = feats16 + (size_t)(j0 + lr) * 128 + quad * 8;

        // acc initialized to the binning bias: (s+1)*204800 + 0.5 rounding
        floatx4 acc[2][8];
        #pragma unroll
        for (int mi = 0; mi < 2; ++mi)
            #pragma unroll
            for (int ni = 0; ni < 8; ++ni) {
                acc[mi][ni][0] = 204800.5f; acc[mi][ni][1] = 204800.5f;
                acc[mi][ni][2] = 204800.5f; acc[mi][ni][3] = 204800.5f;
            }

        #pragma unroll
        for (int ks = 0; ks < 128; ks += 32) {
            half8 af[2];
            #pragma unroll
            for (int mi = 0; mi < 2; ++mi)
                af[mi] = *(const half8*)(Ab + (size_t)mi * 16 * 128 + ks);
            half8 bf[8];
            #pragma unroll
            for (int ni = 0; ni < 8; ++ni)
                bf[ni] = *(const half8*)(Bb + (size_t)ni * 16 * 128 + ks);
            #pragma unroll
            for (int mi = 0; mi < 2; ++mi)
                #pragma unroll
                for (int ni = 0; ni < 8; ++ni)
                    acc[mi][ni] = __builtin_amdgcn_mfma_f32_16x16x32_f16(
                        af[mi], bf[ni], acc[mi][ni], 0, 0, 0);
        }

        // classes for this lane's C fragment rows/cols
        int cA[2][4], cB[8];
        #pragma unroll
        for (int mi = 0; mi < 2; ++mi) {
            int4 c4 = *(const int4*)&cls[0][wave * 32 + mi * 16 + quad * 4];
            cA[mi][0] = c4.x; cA[mi][1] = c4.y;
            cA[mi][2] = c4.z; cA[mi][3] = c4.w;
        }
        #pragma unroll
        for (int ni = 0; ni < 8; ++ni) cB[ni] = cls[1][ni * 16 + lr];

        // binning: acc already equals q + tiny fp noise. One ds_add_u32/pair.
        const int copy = lane & (NCOPY - 1);
        unsigned* hb = &lhist[0][0] + copy;
        const bool diag = (ti == tj);
        #pragma unroll
        for (int mi = 0; mi < 2; ++mi) {
            #pragma unroll
            for (int ni = 0; ni < 8; ++ni) {
                #pragma unroll
                for (int r = 0; r < 4; ++r) {
                    const int li = wave * 32 + mi * 16 + quad * 4 + r;
                    const int lj = ni * 16 + lr;
                    if (diag && li >= lj) continue;  // strict upper triangle
                    float qf = fmaxf(acc[mi][ni][r], 0.0f);
                    unsigned q = (unsigned)qf;
                    q = q > QMAX ? QMAX : q;
                    unsigned idx = q >> 12;
                    unsigned word = (q & 4095u) | (1u << CNT_SHIFT);
                    unsigned hoff = (cA[mi][r] == cB[ni]) ? 0u : (unsigned)NBINS;
                    atomicAdd(hb + (hoff + idx) * NCOPY, word);
                }
            }
        }
    }
    __syncthreads();

    // per-bin unpack: C = sum(w>>22), Fq = sum(w&mask) (q12 fixed point).
    // Max adds per (bin,copy) = 2 lanes * 64 pairs = 128 -> fields safe
    // (cnt <= 128 < 2^10, frac <= 128*4095 < 2^22).
    // Pack (C<<38)|Fq into one u64 atomicAdd; per-block Cs <= 16384 < 2^26,
    // Fq <= 6.7e7 < 2^38; global C-sum 8.39e6 < 2^26, F-sum 3.44e10 < 2^38:
    // carry-free across all 528 blocks.
    if (tid < NB2) {
        unsigned Cs = 0, Fq = 0;
        #pragma unroll
        for (int c = 0; c < NCOPY; ++c) {
            unsigned w = lhist[tid][(c + tid) & (NCOPY - 1)];
            Cs += w >> CNT_SHIFT;
            Fq += w & ((1u << CNT_SHIFT) - 1);
        }
        unsigned long long word =
            ((unsigned long long)Cs << GSHIFT) | (unsigned long long)Fq;
        atomicAdd(&gH[(blockIdx.x & (NREP - 1)) * NB2 + tid], word);
    }
}

// ---------------------------------------------------------------------------
// Tiny finalize: sum 32 replica rows (52KB, unrolled independent loads),
// unpack, telescope, fp64 cumsum.
// ---------------------------------------------------------------------------
__global__ __launch_bounds__(NTHREADS)
void finalize_kernel(const unsigned long long* __restrict__ gH,
                     float* __restrict__ out) {
    __shared__ double Cd[NB2];
    __shared__ double Fd[NB2];
    __shared__ double hd[NB2];
    const int t = threadIdx.x;
    if (t < NB2) {
        unsigned long long w = 0ull;
        #pragma unroll
        for (int r = 0; r < NREP; ++r) w += gH[r * NB2 + t];
        Cd[t] = (double)(w >> GSHIFT);
        Fd[t] = (double)(w & ((1ull << GSHIFT) - 1)) * (1.0 / 4096.0);
    }
    __syncthreads();
    if (t < NB2) {
        const int lo = (t < NBINS) ? 0 : NBINS;
        const int hi = lo + NBINS - 1;
        double h = Cd[t];
        if (t < hi) h -= Fd[t];
        if (t > lo) h += Fd[t - 1];
        hd[t] = h;
    }
    __syncthreads();
    if (t == 0) {
        double sp = 0.0, sn = 0.0;
        for (int k = 0; k < NBINS; ++k) { sp += hd[k]; sn += hd[NBINS + k]; }
        double isp = 1.0 / sp, isn = 1.0 / sn;
        double cdf = 0.0, res = 0.0;
        for (int k = 0; k < NBINS; ++k) {
            cdf += hd[k] * isp;                   // inclusive cumsum of pos
            res += hd[NBINS + k] * isn * cdf;     // dot with neg
        }
        out[0] = (float)res;
    }
}

extern "C" void kernel_launch(void* const* d_in, const int* in_sizes, int n_in,
                              void* d_out, int out_size, void* d_ws, size_t ws_size,
                              hipStream_t stream) {
    const float* feats   = (const float*)d_in[0];
    const int*   classes = (const int*)d_in[1];
    float* out = (float*)d_out;

    int N = in_sizes[1];                       // 4096
    int D = in_sizes[0] / N;                   // 128
    int ntiles = N / 128;                      // 32
    int nblocks = ntiles * (ntiles + 1) / 2;   // 528 blocks, one tile each
    int ngroups = N * D / 8;                   // 65536 groups of 8 floats

    // workspace layout: f16 scaled feats | u64 gH[NREP][NB2]
    _Float16* wsF = (_Float16*)d_ws;
    unsigned long long* gH = (unsigned long long*)(wsF + (size_t)N * D);

    int cblocks = (ngroups + NTHREADS - 1) / NTHREADS;
    convert_kernel<<<cblocks, NTHREADS, 0, stream>>>(feats, wsF, gH, ngroups);
    hist_pairs_kernel<<<nblocks, NTHREADS, 0, stream>>>(wsF, classes, gH, ntiles);
    finalize_kernel<<<1, NTHREADS, 0, stream>>>(gH, out);
}